// Round 1
// baseline (8195.467 us; speedup 1.0000x reference)
//
#include <hip/hip_runtime.h>
#include <math.h>

#define BSZ   16
#define NTOK  197
#define NPAT  196
#define EDIM  768
#define MDIM  256
#define FDIM  3072
#define NLAY  12
#define NCLS  1000
#define TTOT  (BSZ*NTOK)   // 3152
#define TPAT  (BSZ*NPAT)   // 3136
#define XSCALE 0.18995893f // 768^-0.25

__device__ __forceinline__ float4 ld4(const float* p) {
    return *reinterpret_cast<const float4*>(p);
}

// ---------------- patch gather ----------------
__global__ void gather_patches(const float* __restrict__ x, float* __restrict__ patches) {
    int idx = blockIdx.x * 256 + threadIdx.x;          // TPAT*768 total
    if (idx >= TPAT * 768) return;
    int k = idx % 768;
    int t = idx / 768;
    int b = t / NPAT, p = t % NPAT;
    int c = k / 256, r = k % 256;
    int p1 = r / 16, p2 = r % 16;
    int g1 = p / 14, g2 = p % 14;
    patches[idx] = x[(((size_t)b * 3 + c) * 224 + (g1 * 16 + p1)) * 224 + (g2 * 16 + p2)];
}

// ---------------- assemble h = [cls, tok] + pos ----------------
__global__ void assemble_kernel(const float* __restrict__ tok, const float* __restrict__ cls_tok,
                                const float* __restrict__ pos, float* __restrict__ h) {
    int idx = blockIdx.x * 256 + threadIdx.x;          // TTOT*768 exact
    int e = idx % 768;
    int t = idx / 768;
    int b = t / NTOK, n = t % NTOK;
    float v = (n == 0) ? cls_tok[e] : tok[((size_t)(b * NPAT + n - 1)) * 768 + e];
    h[idx] = v + pos[n * 768 + e];
}

// ---------------- generic 64x64x16 tiled fp32 GEMM ----------------
// BT: B stored [N,K] (transposed) vs [K,N].
// EPI: 0 = +bias; 1 = +bias,gelu; 2 = +bias, accumulate into C; 3 = performer (v = acc*XSCALE - diag[row])
template<bool BT, int EPI>
__launch_bounds__(256)
__global__ void gemm64(const float* __restrict__ A, const float* __restrict__ Bm,
                       const float* __restrict__ bias, const float* __restrict__ diag,
                       float* __restrict__ Cd, int Mrows, int Ncols, int Kdim) {
    __shared__ float As[16][64];
    __shared__ float Bs[16][64];
    const int tid = threadIdx.x;
    const int n0 = blockIdx.x * 64;
    const int m0 = blockIdx.y * 64;
    const int tx = tid & 15, ty = tid >> 4;
    float acc[4][4] = {};
    const int lr = tid >> 2;
    const int lc = (tid & 3) << 2;
    for (int k0 = 0; k0 < Kdim; k0 += 16) {
        float4 av = make_float4(0.f, 0.f, 0.f, 0.f);
        int ar = m0 + lr;
        if (ar < Mrows) av = ld4(A + (size_t)ar * Kdim + k0 + lc);
        As[lc + 0][lr] = av.x; As[lc + 1][lr] = av.y;
        As[lc + 2][lr] = av.z; As[lc + 3][lr] = av.w;
        if (!BT) {
            int br = tid >> 4;
            int bc = (tid & 15) << 2;
            float4 bv = ld4(Bm + (size_t)(k0 + br) * Ncols + n0 + bc);
            *reinterpret_cast<float4*>(&Bs[br][bc]) = bv;
        } else {
            int bn = tid >> 2;
            int bk = (tid & 3) << 2;
            float4 bv = ld4(Bm + (size_t)(n0 + bn) * Kdim + k0 + bk);
            Bs[bk + 0][bn] = bv.x; Bs[bk + 1][bn] = bv.y;
            Bs[bk + 2][bn] = bv.z; Bs[bk + 3][bn] = bv.w;
        }
        __syncthreads();
        #pragma unroll
        for (int k = 0; k < 16; ++k) {
            float a[4], bb[4];
            #pragma unroll
            for (int i = 0; i < 4; ++i) a[i] = As[k][ty * 4 + i];
            #pragma unroll
            for (int j = 0; j < 4; ++j) bb[j] = Bs[k][tx * 4 + j];
            #pragma unroll
            for (int i = 0; i < 4; ++i)
                #pragma unroll
                for (int j = 0; j < 4; ++j)
                    acc[i][j] += a[i] * bb[j];
        }
        __syncthreads();
    }
    #pragma unroll
    for (int i = 0; i < 4; ++i) {
        int row = m0 + ty * 4 + i;
        if (row >= Mrows) continue;
        #pragma unroll
        for (int j = 0; j < 4; ++j) {
            int col = n0 + tx * 4 + j;
            float v = acc[i][j];
            if (EPI == 3) {
                v = v * XSCALE - diag[row];
            } else {
                v += bias[col];
            }
            if (EPI == 1) v = 0.5f * v * (1.0f + erff(v * 0.70710678118f));
            size_t o = (size_t)row * Ncols + col;
            if (EPI == 2) v += Cd[o];
            Cd[o] = v;
        }
    }
}

// ---------------- LayerNorm (+ optional performer diag) ----------------
__launch_bounds__(256)
__global__ void ln_kernel(const float* __restrict__ in, int rowStride,
                          const float* __restrict__ g, const float* __restrict__ b,
                          float* __restrict__ out, float* __restrict__ diag) {
    int row = blockIdx.x;
    const float* xr = in + (size_t)row * rowStride;
    int tid = threadIdx.x;
    float v0 = xr[tid], v1 = xr[tid + 256], v2 = xr[tid + 512];
    float s = v0 + v1 + v2;
    float q = v0 * v0 + v1 * v1 + v2 * v2;
    int lane = tid & 63, wid = tid >> 6;
    #pragma unroll
    for (int off = 32; off >= 1; off >>= 1) {
        s += __shfl_down(s, off);
        q += __shfl_down(q, off);
    }
    __shared__ float sh[8];
    __shared__ float mu_s, rs_s;
    if (lane == 0) { sh[wid] = s; sh[4 + wid] = q; }
    __syncthreads();
    if (tid == 0) {
        float ts = sh[0] + sh[1] + sh[2] + sh[3];
        float tq = sh[4] + sh[5] + sh[6] + sh[7];
        float mu = ts * (1.0f / 768.0f);
        float var = tq * (1.0f / 768.0f) - mu * mu;
        mu_s = mu;
        rs_s = rsqrtf(var + 1e-5f);
    }
    __syncthreads();
    float mu = mu_s, rs = rs_s;
    float y0 = (v0 - mu) * rs * g[tid] + b[tid];
    float y1 = (v1 - mu) * rs * g[tid + 256] + b[tid + 256];
    float y2 = (v2 - mu) * rs * g[tid + 512] + b[tid + 512];
    size_t o = (size_t)row * 768;
    out[o + tid] = y0;
    out[o + tid + 256] = y1;
    out[o + tid + 512] = y2;
    if (diag) {
        float qq = y0 * y0 + y1 * y1 + y2 * y2;
        #pragma unroll
        for (int off = 32; off >= 1; off >>= 1) qq += __shfl_down(qq, off);
        if (lane == 0) sh[wid] = qq;
        __syncthreads();
        if (tid == 0) diag[row] = 0.5f * XSCALE * XSCALE * (sh[0] + sh[1] + sh[2] + sh[3]);
    }
}

// ---------------- per-row max over M=256 ----------------
__launch_bounds__(64)
__global__ void rowmax_kernel(const float* __restrict__ lg, float* __restrict__ rmax) {
    int row = blockIdx.x;
    int lane = threadIdx.x;
    const float* r = lg + (size_t)row * 256;
    float m = fmaxf(fmaxf(r[lane], r[lane + 64]), fmaxf(r[lane + 128], r[lane + 192]));
    #pragma unroll
    for (int off = 32; off >= 1; off >>= 1) m = fmaxf(m, __shfl_down(m, off));
    if (lane == 0) rmax[row] = m;
}

// ---------------- global max over rowmax ----------------
__launch_bounds__(256)
__global__ void gmax_kernel(const float* __restrict__ rmax, float* __restrict__ gmax) {
    int tid = threadIdx.x;
    float m = -1e30f;
    for (int i = tid; i < TTOT; i += 256) m = fmaxf(m, rmax[i]);
    int lane = tid & 63, wid = tid >> 6;
    #pragma unroll
    for (int off = 32; off >= 1; off >>= 1) m = fmaxf(m, __shfl_down(m, off));
    __shared__ float sh[4];
    if (lane == 0) sh[wid] = m;
    __syncthreads();
    if (tid == 0) gmax[0] = fmaxf(fmaxf(sh[0], sh[1]), fmaxf(sh[2], sh[3]));
}

// ---------------- features: q_feat, k_feat ----------------
__global__ void feat_kernel(const float* __restrict__ lg, const float* __restrict__ rmax,
                            const float* __restrict__ gmax, float* __restrict__ qf,
                            float* __restrict__ kf) {
    int idx = blockIdx.x * 256 + threadIdx.x;  // TTOT*256 exact
    int row = idx >> 8;
    float v = lg[idx];
    qf[idx] = expf(v - rmax[row]) * 0.0625f + 1e-4f;
    kf[idx] = expf(v - gmax[0]) * 0.0625f + 1e-4f;
}

// ---------------- kv[b,m,e] = sum_n kf[b,n,m] * xln[b,n,e]; ksum[b,m] ----------------
__launch_bounds__(256)
__global__ void kv_kernel(const float* __restrict__ kf, const float* __restrict__ xln,
                          float* __restrict__ kv, float* __restrict__ ksum) {
    int blk = blockIdx.x;            // BSZ*32
    int b = blk >> 5;
    int m0 = (blk & 31) << 3;        // 8 m's per block
    __shared__ float kc[NTOK * 8];
    int tid = threadIdx.x;
    for (int i = tid; i < NTOK * 8; i += 256) {
        int n = i >> 3, j = i & 7;
        kc[i] = kf[((size_t)(b * NTOK + n)) * 256 + m0 + j];
    }
    __syncthreads();
    if (tid < 8) {
        float s = 0.f;
        for (int n = 0; n < NTOK; ++n) s += kc[n * 8 + tid];
        ksum[b * 256 + m0 + tid] = s;
    }
    float acc[8][3] = {};
    const float* xb = xln + (size_t)b * NTOK * 768;
    for (int n = 0; n < NTOK; ++n) {
        float x0 = xb[n * 768 + tid];
        float x1 = xb[n * 768 + tid + 256];
        float x2 = xb[n * 768 + tid + 512];
        #pragma unroll
        for (int j = 0; j < 8; ++j) {
            float kk = kc[n * 8 + j];
            acc[j][0] += kk * x0;
            acc[j][1] += kk * x1;
            acc[j][2] += kk * x2;
        }
    }
    float* kvb = kv + ((size_t)b * 256 + m0) * 768;
    #pragma unroll
    for (int j = 0; j < 8; ++j) {
        kvb[j * 768 + tid] = acc[j][0];
        kvb[j * 768 + tid + 256] = acc[j][1];
        kvb[j * 768 + tid + 512] = acc[j][2];
    }
}

// ---------------- att: h += (qf @ kv) / den ----------------
__launch_bounds__(256)
__global__ void att_kernel(const float* __restrict__ qf, const float* __restrict__ ksum,
                           const float* __restrict__ kv, float* __restrict__ h) {
    int blk = blockIdx.x;            // BSZ*25
    int b = blk / 25;
    int n0 = (blk % 25) * 8;
    int nrows = NTOK - n0; if (nrows > 8) nrows = 8;
    __shared__ float qs[8][256];
    __shared__ float dinv[8];
    __shared__ float sh[4];
    int tid = threadIdx.x;
    for (int r = 0; r < nrows; ++r)
        qs[r][tid] = qf[((size_t)(b * NTOK + n0 + r)) * 256 + tid];
    for (int r = nrows; r < 8; ++r) qs[r][tid] = 0.f;
    __syncthreads();
    int lane = tid & 63, wid = tid >> 6;
    float ks = ksum[b * 256 + tid];
    for (int r = 0; r < nrows; ++r) {
        float d = qs[r][tid] * ks;
        #pragma unroll
        for (int off = 32; off >= 1; off >>= 1) d += __shfl_down(d, off);
        if (lane == 0) sh[wid] = d;
        __syncthreads();
        if (tid == 0) dinv[r] = 1.0f / (sh[0] + sh[1] + sh[2] + sh[3]);
        __syncthreads();
    }
    float acc[8][3] = {};
    const float* kvb = kv + (size_t)b * 256 * 768;
    for (int m = 0; m < 256; ++m) {
        float k0 = kvb[m * 768 + tid];
        float k1 = kvb[m * 768 + tid + 256];
        float k2 = kvb[m * 768 + tid + 512];
        #pragma unroll
        for (int r = 0; r < 8; ++r) {
            float qv = qs[r][m];
            acc[r][0] += qv * k0;
            acc[r][1] += qv * k1;
            acc[r][2] += qv * k2;
        }
    }
    for (int r = 0; r < nrows; ++r) {
        float di = dinv[r];
        size_t o = ((size_t)(b * NTOK + n0 + r)) * 768;
        h[o + tid]       += acc[r][0] * di;
        h[o + tid + 256] += acc[r][1] * di;
        h[o + tid + 512] += acc[r][2] * di;
    }
}

// ---------------- classifier head ----------------
__global__ void head_kernel(const float* __restrict__ cls, const float* __restrict__ w,
                            const float* __restrict__ hb, float* __restrict__ out) {
    int idx = blockIdx.x * 256 + threadIdx.x;
    if (idx >= BSZ * NCLS) return;
    int i = idx / NCLS, j = idx % NCLS;
    float acc = hb[j];
    const float* cr = cls + (size_t)i * 768;
    for (int k = 0; k < 768; ++k) acc += cr[k] * w[k * NCLS + j];
    out[idx] = acc;
}

extern "C" void kernel_launch(void* const* d_in, const int* in_sizes, int n_in,
                              void* d_out, int out_size, void* d_ws, size_t ws_size,
                              hipStream_t stream) {
    const float* x       = (const float*)d_in[0];
    const float* cls_tok = (const float*)d_in[1];
    const float* pos_emb = (const float*)d_in[2];
    const float* patch_w = (const float*)d_in[3];
    const float* patch_b = (const float*)d_in[4];
    const float* ln1_g   = (const float*)d_in[5];
    const float* ln1_b   = (const float*)d_in[6];
    const float* proj    = (const float*)d_in[7];
    const float* ln2_g   = (const float*)d_in[8];
    const float* ln2_b   = (const float*)d_in[9];
    const float* w1      = (const float*)d_in[10];
    const float* b1      = (const float*)d_in[11];
    const float* w2      = (const float*)d_in[12];
    const float* b2      = (const float*)d_in[13];
    const float* lnf_g   = (const float*)d_in[14];
    const float* lnf_b   = (const float*)d_in[15];
    const float* head_w  = (const float*)d_in[16];
    const float* head_b  = (const float*)d_in[17];
    float* out = (float*)d_out;

    float* ws = (float*)d_ws;
    // region 0 (aliased): [patches | tok] during embed, y1 during MLP
    float* patches = ws;                       // 2,408,448
    float* tok     = ws + 2408448;             // 2,408,448
    float* y1      = ws;                       // 9,682,944 (alias, used after embed)
    size_t off = 9682944;
    float* h     = ws + off; off += 2420736;   // [3152,768]
    float* xln   = ws + off; off += 2420736;   // [3152,768]
    float* lg    = ws + off; off += 806912;    // [3152,256]
    float* qf    = ws + off; off += 806912;
    float* kf    = ws + off; off += 806912;
    float* kv    = ws + off; off += 3145728;   // [16,256,768]
    float* diag  = ws + off; off += 3152;
    float* rmax  = ws + off; off += 3152;
    float* gmaxp = ws + off; off += 64;
    float* ksum  = ws + off; off += 4096;
    float* clsln = ws + off; off += 12288;

    // --- patch embedding ---
    gather_patches<<<9408, 256, 0, stream>>>(x, patches);
    gemm64<true, 0><<<dim3(768 / 64, TPAT / 64), 256, 0, stream>>>(
        patches, patch_w, patch_b, nullptr, tok, TPAT, 768, 768);
    assemble_kernel<<<9456, 256, 0, stream>>>(tok, cls_tok, pos_emb, h);

    // --- transformer layers ---
    for (int l = 0; l < NLAY; ++l) {
        ln_kernel<<<TTOT, 256, 0, stream>>>(h, 768, ln1_g + l * 768, ln1_b + l * 768, xln, diag);
        gemm64<true, 3><<<dim3(256 / 64, (TTOT + 63) / 64), 256, 0, stream>>>(
            xln, proj + (size_t)l * 256 * 768, nullptr, diag, lg, TTOT, 256, 768);
        rowmax_kernel<<<TTOT, 64, 0, stream>>>(lg, rmax);
        gmax_kernel<<<1, 256, 0, stream>>>(rmax, gmaxp);
        feat_kernel<<<TTOT, 256, 0, stream>>>(lg, rmax, gmaxp, qf, kf);
        kv_kernel<<<BSZ * 32, 256, 0, stream>>>(kf, xln, kv, ksum);
        att_kernel<<<BSZ * 25, 256, 0, stream>>>(qf, ksum, kv, h);
        ln_kernel<<<TTOT, 256, 0, stream>>>(h, 768, ln2_g + l * 768, ln2_b + l * 768, xln, nullptr);
        gemm64<false, 1><<<dim3(FDIM / 64, (TTOT + 63) / 64), 256, 0, stream>>>(
            xln, w1 + (size_t)l * 768 * FDIM, b1 + l * FDIM, nullptr, y1, TTOT, FDIM, 768);
        gemm64<false, 2><<<dim3(768 / 64, (TTOT + 63) / 64), 256, 0, stream>>>(
            y1, w2 + (size_t)l * FDIM * 768, b2 + l * 768, nullptr, h, TTOT, 768, FDIM);
    }

    // --- final LN on cls tokens + head ---
    ln_kernel<<<BSZ, 256, 0, stream>>>(h, NTOK * 768, lnf_g, lnf_b, clsln, nullptr);
    head_kernel<<<(BSZ * NCLS + 255) / 256, 256, 0, stream>>>(clsln, head_w, head_b, out);
}

// Round 2
// 3798.204 us; speedup vs baseline: 2.1577x; 2.1577x over previous
//
#include <hip/hip_runtime.h>
#include <math.h>

#define BSZ   16
#define NTOK  197
#define NPAT  196
#define EDIM  768
#define MDIM  256
#define FDIM  3072
#define NLAY  12
#define NCLS  1000
#define TTOT  (BSZ*NTOK)   // 3152
#define TPAT  (BSZ*NPAT)   // 3136
#define XSCALE 0.18995893f // 768^-0.25

typedef unsigned short ushortT;
typedef short s16x8 __attribute__((ext_vector_type(8)));
typedef float f32x4 __attribute__((ext_vector_type(4)));

__device__ __forceinline__ float4 ld4(const float* p) {
    return *reinterpret_cast<const float4*>(p);
}
__device__ __forceinline__ ushortT f2bf(float f) {
    unsigned u = __builtin_bit_cast(unsigned, f);
    unsigned r = (u + 0x7fff + ((u >> 16) & 1)) >> 16;
    return (ushortT)r;
}
__device__ __forceinline__ float bf2f(ushortT u) {
    return __builtin_bit_cast(float, ((unsigned)u) << 16);
}
__device__ __forceinline__ void load_lds16(const ushortT* g, ushortT* lds) {
    __builtin_amdgcn_global_load_lds(
        (const __attribute__((address_space(1))) unsigned int*)g,
        (__attribute__((address_space(3))) unsigned int*)lds, 16, 0, 0);
}

// ---------------- patch gather (bf16 out) ----------------
__global__ void gather_patches(const float* __restrict__ x, ushortT* __restrict__ patches) {
    int idx = blockIdx.x * 256 + threadIdx.x;          // TPAT*768 total
    if (idx >= TPAT * 768) return;
    int k = idx % 768;
    int t = idx / 768;
    int b = t / NPAT, p = t % NPAT;
    int c = k / 256, r = k % 256;
    int p1 = r / 16, p2 = r % 16;
    int g1 = p / 14, g2 = p % 14;
    patches[idx] = f2bf(x[(((size_t)b * 3 + c) * 224 + (g1 * 16 + p1)) * 224 + (g2 * 16 + p2)]);
}

// ---------------- assemble h = [cls, tok] + pos ----------------
__global__ void assemble_kernel(const float* __restrict__ tok, const float* __restrict__ cls_tok,
                                const float* __restrict__ pos, float* __restrict__ h) {
    int idx = blockIdx.x * 256 + threadIdx.x;          // TTOT*768 exact
    int e = idx % 768;
    int t = idx / 768;
    int b = t / NTOK, n = t % NTOK;
    float v = (n == 0) ? cls_tok[e] : tok[((size_t)(b * NPAT + n - 1)) * 768 + e];
    h[idx] = v + pos[n * 768 + e];
}

// ---------------- fp32 → bf16 elementwise ----------------
__global__ void cvt_bf16(const float* __restrict__ in, ushortT* __restrict__ out, int n) {
    int idx = blockIdx.x * 256 + threadIdx.x;
    if (idx < n) out[idx] = f2bf(in[idx]);
}

// ---------------- fp32 [R,C] → bf16 [C,R] transpose (R,C multiples of 32) ----------------
__launch_bounds__(256)
__global__ void transpose_cvt(const float* __restrict__ in, ushortT* __restrict__ out,
                              int R, int Ccol) {
    __shared__ float tile[32][33];
    int c0 = blockIdx.x * 32, r0 = blockIdx.y * 32;
    int tx = threadIdx.x & 31, ty = threadIdx.x >> 5;
    #pragma unroll
    for (int i = 0; i < 32; i += 8)
        tile[ty + i][tx] = in[(size_t)(r0 + ty + i) * Ccol + c0 + tx];
    __syncthreads();
    #pragma unroll
    for (int i = 0; i < 32; i += 8)
        out[(size_t)(c0 + ty + i) * R + r0 + tx] = f2bf(tile[tx][ty + i]);
}

// ---------------- bf16 MFMA GEMM, m97 structure: 128x128 tile, BK=32 ----------------
// A [M,K] bf16 (rows padded to m-tile), Bt [N,K] bf16. fp32 accum.
// EPI: 0 = +bias → fp32 C; 1 = +bias, gelu → bf16 Cb; 2 = +bias, += residual fp32 C
template<int EPI>
__launch_bounds__(256)
__global__ void mgemm(const ushortT* __restrict__ A, const ushortT* __restrict__ Bt,
                      const float* __restrict__ bias, float* __restrict__ C,
                      ushortT* __restrict__ Cb, int M, int N, int K) {
    __shared__ ushortT As[128 * 32];
    __shared__ ushortT Bs[128 * 32];
    const int t = threadIdx.x;
    const int n0 = blockIdx.x * 128;
    const int m0 = blockIdx.y * 128;
    const int lane = t & 63;
    const int wv = t >> 6;
    const int wm = (wv >> 1) * 64;
    const int wn = (wv & 1) * 64;
    f32x4 acc[4][4];
    #pragma unroll
    for (int i = 0; i < 4; ++i)
        #pragma unroll
        for (int j = 0; j < 4; ++j) acc[i][j] = (f32x4)0.f;

    const ushortT* aptr = A + (size_t)(m0 + (t >> 2)) * K + (t & 3) * 8;
    const ushortT* bptr = Bt + (size_t)(n0 + (t >> 2)) * K + (t & 3) * 8;
    ushortT* aLds = As + t * 8;
    ushortT* bLds = Bs + t * 8;
    const size_t rowStep = (size_t)64 * K;

    const int fr = lane & 15;
    const int fko = (lane >> 4) * 8;
    const ushortT* aRd = As + (wm + fr) * 32 + fko;
    const ushortT* bRd = Bs + (wn + fr) * 32 + fko;

    for (int k0 = 0; k0 < K; k0 += 32) {
        load_lds16(aptr, aLds);
        load_lds16(aptr + rowStep, aLds + 2048);
        load_lds16(bptr, bLds);
        load_lds16(bptr + rowStep, bLds + 2048);
        aptr += 32; bptr += 32;
        __syncthreads();
        s16x8 af[4], bfr[4];
        #pragma unroll
        for (int i = 0; i < 4; ++i) af[i] = *(const s16x8*)(aRd + i * 512);
        #pragma unroll
        for (int j = 0; j < 4; ++j) bfr[j] = *(const s16x8*)(bRd + j * 512);
        #pragma unroll
        for (int i = 0; i < 4; ++i)
            #pragma unroll
            for (int j = 0; j < 4; ++j)
                acc[i][j] = __builtin_amdgcn_mfma_f32_16x16x32_bf16(af[i], bfr[j], acc[i][j], 0, 0, 0);
        __syncthreads();
    }

    const int orow = (lane >> 4) * 4;
    const int ocol = lane & 15;
    #pragma unroll
    for (int i = 0; i < 4; ++i) {
        #pragma unroll
        for (int r = 0; r < 4; ++r) {
            int row = m0 + wm + i * 16 + orow + r;
            if (row >= M) continue;
            #pragma unroll
            for (int j = 0; j < 4; ++j) {
                int col = n0 + wn + j * 16 + ocol;
                float v = acc[i][j][r] + bias[col];
                size_t o = (size_t)row * N + col;
                if (EPI == 0) {
                    C[o] = v;
                } else if (EPI == 1) {
                    v = 0.5f * v * (1.0f + erff(v * 0.70710678118f));
                    Cb[o] = f2bf(v);
                } else {
                    C[o] = C[o] + v;
                }
            }
        }
    }
}

// ---------------- fp32 64x64 tiled GEMM (performer logits only) ----------------
// Bt stored [N,K]. EPI3: v = acc*XSCALE - diag[row]
__launch_bounds__(256)
__global__ void gemm64_lg(const float* __restrict__ A, const float* __restrict__ Bm,
                          const float* __restrict__ diag, float* __restrict__ Cd,
                          int Mrows, int Ncols, int Kdim) {
    __shared__ float As[16][64];
    __shared__ float Bs[16][64];
    const int tid = threadIdx.x;
    const int n0 = blockIdx.x * 64;
    const int m0 = blockIdx.y * 64;
    const int tx = tid & 15, ty = tid >> 4;
    float acc[4][4] = {};
    const int lr = tid >> 2;
    const int lc = (tid & 3) << 2;
    for (int k0 = 0; k0 < Kdim; k0 += 16) {
        float4 av = make_float4(0.f, 0.f, 0.f, 0.f);
        int ar = m0 + lr;
        if (ar < Mrows) av = ld4(A + (size_t)ar * Kdim + k0 + lc);
        As[lc + 0][lr] = av.x; As[lc + 1][lr] = av.y;
        As[lc + 2][lr] = av.z; As[lc + 3][lr] = av.w;
        int bn = tid >> 2;
        int bk = (tid & 3) << 2;
        float4 bv = ld4(Bm + (size_t)(n0 + bn) * Kdim + k0 + bk);
        Bs[bk + 0][bn] = bv.x; Bs[bk + 1][bn] = bv.y;
        Bs[bk + 2][bn] = bv.z; Bs[bk + 3][bn] = bv.w;
        __syncthreads();
        #pragma unroll
        for (int k = 0; k < 16; ++k) {
            float a[4], bb[4];
            #pragma unroll
            for (int i = 0; i < 4; ++i) a[i] = As[k][ty * 4 + i];
            #pragma unroll
            for (int j = 0; j < 4; ++j) bb[j] = Bs[k][tx * 4 + j];
            #pragma unroll
            for (int i = 0; i < 4; ++i)
                #pragma unroll
                for (int j = 0; j < 4; ++j)
                    acc[i][j] += a[i] * bb[j];
        }
        __syncthreads();
    }
    #pragma unroll
    for (int i = 0; i < 4; ++i) {
        int row = m0 + ty * 4 + i;
        if (row >= Mrows) continue;
        #pragma unroll
        for (int j = 0; j < 4; ++j) {
            int col = n0 + tx * 4 + j;
            Cd[(size_t)row * Ncols + col] = acc[i][j] * XSCALE - diag[row];
        }
    }
}

// ---------------- LayerNorm: fp32 out + bf16 out (+ optional performer diag) ----------------
__launch_bounds__(256)
__global__ void ln_kernel(const float* __restrict__ in, int rowStride,
                          const float* __restrict__ g, const float* __restrict__ b,
                          float* __restrict__ out, ushortT* __restrict__ outb,
                          float* __restrict__ diag) {
    int row = blockIdx.x;
    const float* xr = in + (size_t)row * rowStride;
    int tid = threadIdx.x;
    float v0 = xr[tid], v1 = xr[tid + 256], v2 = xr[tid + 512];
    float s = v0 + v1 + v2;
    float q = v0 * v0 + v1 * v1 + v2 * v2;
    int lane = tid & 63, wid = tid >> 6;
    #pragma unroll
    for (int off = 32; off >= 1; off >>= 1) {
        s += __shfl_down(s, off);
        q += __shfl_down(q, off);
    }
    __shared__ float sh[8];
    __shared__ float mu_s, rs_s;
    if (lane == 0) { sh[wid] = s; sh[4 + wid] = q; }
    __syncthreads();
    if (tid == 0) {
        float ts = sh[0] + sh[1] + sh[2] + sh[3];
        float tq = sh[4] + sh[5] + sh[6] + sh[7];
        float mu = ts * (1.0f / 768.0f);
        float var = tq * (1.0f / 768.0f) - mu * mu;
        mu_s = mu;
        rs_s = rsqrtf(var + 1e-5f);
    }
    __syncthreads();
    float mu = mu_s, rs = rs_s;
    float y0 = (v0 - mu) * rs * g[tid] + b[tid];
    float y1 = (v1 - mu) * rs * g[tid + 256] + b[tid + 256];
    float y2 = (v2 - mu) * rs * g[tid + 512] + b[tid + 512];
    size_t o = (size_t)row * 768;
    out[o + tid] = y0;
    out[o + tid + 256] = y1;
    out[o + tid + 512] = y2;
    outb[o + tid] = f2bf(y0);
    outb[o + tid + 256] = f2bf(y1);
    outb[o + tid + 512] = f2bf(y2);
    if (diag) {
        float qq = y0 * y0 + y1 * y1 + y2 * y2;
        #pragma unroll
        for (int off = 32; off >= 1; off >>= 1) qq += __shfl_down(qq, off);
        if (lane == 0) sh[wid] = qq;
        __syncthreads();
        if (tid == 0) diag[row] = 0.5f * XSCALE * XSCALE * (sh[0] + sh[1] + sh[2] + sh[3]);
    }
}

// ---------------- per-row max over M=256 ----------------
__launch_bounds__(64)
__global__ void rowmax_kernel(const float* __restrict__ lg, float* __restrict__ rmax) {
    int row = blockIdx.x;
    int lane = threadIdx.x;
    const float* r = lg + (size_t)row * 256;
    float m = fmaxf(fmaxf(r[lane], r[lane + 64]), fmaxf(r[lane + 128], r[lane + 192]));
    #pragma unroll
    for (int off = 32; off >= 1; off >>= 1) m = fmaxf(m, __shfl_down(m, off));
    if (lane == 0) rmax[row] = m;
}

// ---------------- global max over rowmax ----------------
__launch_bounds__(256)
__global__ void gmax_kernel(const float* __restrict__ rmax, float* __restrict__ gmax) {
    int tid = threadIdx.x;
    float m = -1e30f;
    for (int i = tid; i < TTOT; i += 256) m = fmaxf(m, rmax[i]);
    int lane = tid & 63, wid = tid >> 6;
    #pragma unroll
    for (int off = 32; off >= 1; off >>= 1) m = fmaxf(m, __shfl_down(m, off));
    __shared__ float sh[4];
    if (lane == 0) sh[wid] = m;
    __syncthreads();
    if (tid == 0) gmax[0] = fmaxf(fmaxf(sh[0], sh[1]), fmaxf(sh[2], sh[3]));
}

// ---------------- features: q_feat, k_feat ----------------
__global__ void feat_kernel(const float* __restrict__ lg, const float* __restrict__ rmax,
                            const float* __restrict__ gmax, float* __restrict__ qf,
                            float* __restrict__ kf) {
    int idx = blockIdx.x * 256 + threadIdx.x;  // TTOT*256 exact
    int row = idx >> 8;
    float v = lg[idx];
    qf[idx] = expf(v - rmax[row]) * 0.0625f + 1e-4f;
    kf[idx] = expf(v - gmax[0]) * 0.0625f + 1e-4f;
}

// ---------------- kv[b,m,e] = sum_n kf[b,n,m] * xln[b,n,e]; ksum[b,m] ----------------
__launch_bounds__(256)
__global__ void kv_kernel(const float* __restrict__ kf, const float* __restrict__ xln,
                          float* __restrict__ kv, float* __restrict__ ksum) {
    int blk = blockIdx.x;            // BSZ*32
    int b = blk >> 5;
    int m0 = (blk & 31) << 3;        // 8 m's per block
    __shared__ float kc[NTOK * 8];
    int tid = threadIdx.x;
    for (int i = tid; i < NTOK * 8; i += 256) {
        int n = i >> 3, j = i & 7;
        kc[i] = kf[((size_t)(b * NTOK + n)) * 256 + m0 + j];
    }
    __syncthreads();
    if (tid < 8) {
        float s = 0.f;
        for (int n = 0; n < NTOK; ++n) s += kc[n * 8 + tid];
        ksum[b * 256 + m0 + tid] = s;
    }
    float acc[8][3] = {};
    const float* xb = xln + (size_t)b * NTOK * 768;
    for (int n = 0; n < NTOK; ++n) {
        float x0 = xb[n * 768 + tid];
        float x1 = xb[n * 768 + tid + 256];
        float x2 = xb[n * 768 + tid + 512];
        #pragma unroll
        for (int j = 0; j < 8; ++j) {
            float kk = kc[n * 8 + j];
            acc[j][0] += kk * x0;
            acc[j][1] += kk * x1;
            acc[j][2] += kk * x2;
        }
    }
    float* kvb = kv + ((size_t)b * 256 + m0) * 768;
    #pragma unroll
    for (int j = 0; j < 8; ++j) {
        kvb[j * 768 + tid] = acc[j][0];
        kvb[j * 768 + tid + 256] = acc[j][1];
        kvb[j * 768 + tid + 512] = acc[j][2];
    }
}

// ---------------- att: h += (qf @ kv) / den ----------------
__launch_bounds__(256)
__global__ void att_kernel(const float* __restrict__ qf, const float* __restrict__ ksum,
                           const float* __restrict__ kv, float* __restrict__ h) {
    int blk = blockIdx.x;            // BSZ*25
    int b = blk / 25;
    int n0 = (blk % 25) * 8;
    int nrows = NTOK - n0; if (nrows > 8) nrows = 8;
    __shared__ float qs[8][256];
    __shared__ float dinv[8];
    __shared__ float sh[4];
    int tid = threadIdx.x;
    for (int r = 0; r < nrows; ++r)
        qs[r][tid] = qf[((size_t)(b * NTOK + n0 + r)) * 256 + tid];
    for (int r = nrows; r < 8; ++r) qs[r][tid] = 0.f;
    __syncthreads();
    int lane = tid & 63, wid = tid >> 6;
    float ks = ksum[b * 256 + tid];
    for (int r = 0; r < nrows; ++r) {
        float d = qs[r][tid] * ks;
        #pragma unroll
        for (int off = 32; off >= 1; off >>= 1) d += __shfl_down(d, off);
        if (lane == 0) sh[wid] = d;
        __syncthreads();
        if (tid == 0) dinv[r] = 1.0f / (sh[0] + sh[1] + sh[2] + sh[3]);
        __syncthreads();
    }
    float acc[8][3] = {};
    const float* kvb = kv + (size_t)b * 256 * 768;
    for (int m = 0; m < 256; ++m) {
        float k0 = kvb[m * 768 + tid];
        float k1 = kvb[m * 768 + tid + 256];
        float k2 = kvb[m * 768 + tid + 512];
        #pragma unroll
        for (int r = 0; r < 8; ++r) {
            float qv = qs[r][m];
            acc[r][0] += qv * k0;
            acc[r][1] += qv * k1;
            acc[r][2] += qv * k2;
        }
    }
    for (int r = 0; r < nrows; ++r) {
        float di = dinv[r];
        size_t o = ((size_t)(b * NTOK + n0 + r)) * 768;
        h[o + tid]       += acc[r][0] * di;
        h[o + tid + 256] += acc[r][1] * di;
        h[o + tid + 512] += acc[r][2] * di;
    }
}

// ---------------- classifier head ----------------
__global__ void head_kernel(const float* __restrict__ cls, const float* __restrict__ w,
                            const float* __restrict__ hb, float* __restrict__ out) {
    int idx = blockIdx.x * 256 + threadIdx.x;
    if (idx >= BSZ * NCLS) return;
    int i = idx / NCLS, j = idx % NCLS;
    float acc = hb[j];
    const float* cr = cls + (size_t)i * 768;
    for (int k = 0; k < 768; ++k) acc += cr[k] * w[k * NCLS + j];
    out[idx] = acc;
}

extern "C" void kernel_launch(void* const* d_in, const int* in_sizes, int n_in,
                              void* d_out, int out_size, void* d_ws, size_t ws_size,
                              hipStream_t stream) {
    const float* x       = (const float*)d_in[0];
    const float* cls_tok = (const float*)d_in[1];
    const float* pos_emb = (const float*)d_in[2];
    const float* patch_w = (const float*)d_in[3];
    const float* patch_b = (const float*)d_in[4];
    const float* ln1_g   = (const float*)d_in[5];
    const float* ln1_b   = (const float*)d_in[6];
    const float* proj    = (const float*)d_in[7];
    const float* ln2_g   = (const float*)d_in[8];
    const float* ln2_b   = (const float*)d_in[9];
    const float* w1      = (const float*)d_in[10];
    const float* b1      = (const float*)d_in[11];
    const float* w2      = (const float*)d_in[12];
    const float* b2      = (const float*)d_in[13];
    const float* lnf_g   = (const float*)d_in[14];
    const float* lnf_b   = (const float*)d_in[15];
    const float* head_w  = (const float*)d_in[16];
    const float* head_b  = (const float*)d_in[17];
    float* out = (float*)d_out;

    char* wsb = (char*)d_ws;
    // region A (aliased): y1b [3200x3072 bf16] in loop; pre-loop: tok fp32 + patches bf16
    ushortT* y1b        = (ushortT*)wsb;                       // 19,660,800 B
    float*   tok        = (float*)wsb;                         // 9,633,792 B
    ushortT* patches_bf = (ushortT*)(wsb + 9633792);           // 4,915,200 B
    size_t off = 19660800;
    float*   h      = (float*)(wsb + off); off += 9682944;     // [3152,768]
    float*   xln    = (float*)(wsb + off); off += 9830400;     // [3200,768] fp32
    ushortT* xln_bf = (ushortT*)(wsb + off); off += 4915200;   // [3200,768] bf16
    float*   lg     = (float*)(wsb + off); off += 3227648;     // [3152,256]
    float*   qf     = (float*)(wsb + off); off += 3227648;
    float*   kf     = (float*)(wsb + off); off += 3227648;
    float*   kv     = (float*)(wsb + off); off += 12582912;    // [16,256,768]
    ushortT* w1t    = (ushortT*)(wsb + off); off += 4718592;   // [3072,768] bf16
    ushortT* w2t    = (ushortT*)(wsb + off); off += 4718592;   // [768,3072] bf16
    ushortT* pwb    = (ushortT*)(wsb + off); off += 1179648;   // [768,768] bf16
    float*   diag   = (float*)(wsb + off); off += 12800;
    float*   rmax   = (float*)(wsb + off); off += 12800;
    float*   gmaxp  = (float*)(wsb + off); off += 256;
    float*   ksum   = (float*)(wsb + off); off += 16384;
    float*   clsln  = (float*)(wsb + off); off += 49152;

    // --- patch embedding (bf16 MFMA) ---
    gather_patches<<<9408, 256, 0, stream>>>(x, patches_bf);
    cvt_bf16<<<2304, 256, 0, stream>>>(patch_w, pwb, 768 * 768);
    mgemm<0><<<dim3(6, 25), 256, 0, stream>>>(patches_bf, pwb, patch_b, tok, nullptr,
                                              TPAT, 768, 768);
    assemble_kernel<<<9456, 256, 0, stream>>>(tok, cls_tok, pos_emb, h);

    // --- transformer layers ---
    for (int l = 0; l < NLAY; ++l) {
        // weight conversion for this layer (bf16, transposed to [N,K])
        transpose_cvt<<<dim3(96, 24), 256, 0, stream>>>(w1 + (size_t)l * 768 * FDIM, w1t, 768, FDIM);
        transpose_cvt<<<dim3(24, 96), 256, 0, stream>>>(w2 + (size_t)l * FDIM * 768, w2t, FDIM, 768);

        ln_kernel<<<TTOT, 256, 0, stream>>>(h, 768, ln1_g + l * 768, ln1_b + l * 768,
                                            xln, xln_bf, diag);
        gemm64_lg<<<dim3(4, 50), 256, 0, stream>>>(xln, proj + (size_t)l * 256 * 768,
                                                   diag, lg, TTOT, 256, 768);
        rowmax_kernel<<<TTOT, 64, 0, stream>>>(lg, rmax);
        gmax_kernel<<<1, 256, 0, stream>>>(rmax, gmaxp);
        feat_kernel<<<TTOT, 256, 0, stream>>>(lg, rmax, gmaxp, qf, kf);
        kv_kernel<<<BSZ * 32, 256, 0, stream>>>(kf, xln, kv, ksum);
        att_kernel<<<BSZ * 25, 256, 0, stream>>>(qf, ksum, kv, h);
        ln_kernel<<<TTOT, 256, 0, stream>>>(h, 768, ln2_g + l * 768, ln2_b + l * 768,
                                            xln, xln_bf, nullptr);
        mgemm<1><<<dim3(24, 25), 256, 0, stream>>>(xln_bf, w1t, b1 + l * FDIM,
                                                   nullptr, y1b, TTOT, FDIM, 768);
        mgemm<2><<<dim3(6, 25), 256, 0, stream>>>(y1b, w2t, b2 + l * 768,
                                                  h, nullptr, TTOT, 768, FDIM);
    }

    // --- final LN on cls tokens + head ---
    ln_kernel<<<BSZ, 256, 0, stream>>>(h, NTOK * 768, lnf_g, lnf_b, clsln, xln_bf, nullptr);
    head_kernel<<<(BSZ * NCLS + 255) / 256, 256, 0, stream>>>(clsln, head_w, head_b, out);
}

// Round 3
// 3690.157 us; speedup vs baseline: 2.2209x; 1.0293x over previous
//
#include <hip/hip_runtime.h>
#include <math.h>

#define BSZ   16
#define NTOK  197
#define NPAT  196
#define EDIM  768
#define MDIM  256
#define FDIM  3072
#define NLAY  12
#define NCLS  1000
#define TTOT  (BSZ*NTOK)   // 3152
#define TPAT  (BSZ*NPAT)   // 3136
#define XSCALE 0.18995893f // 768^-0.25

typedef unsigned short ushortT;
typedef short s16x8 __attribute__((ext_vector_type(8)));
typedef float f32x4 __attribute__((ext_vector_type(4)));

__device__ __forceinline__ float4 ld4(const float* p) {
    return *reinterpret_cast<const float4*>(p);
}
__device__ __forceinline__ ushortT f2bf(float f) {
    unsigned u = __builtin_bit_cast(unsigned, f);
    unsigned r = (u + 0x7fff + ((u >> 16) & 1)) >> 16;
    return (ushortT)r;
}
__device__ __forceinline__ void load_lds16(const ushortT* g, ushortT* lds) {
    __builtin_amdgcn_global_load_lds(
        (const __attribute__((address_space(1))) unsigned int*)g,
        (__attribute__((address_space(3))) unsigned int*)lds, 16, 0, 0);
}
// order-preserving float<->uint encoding for atomicMax over floats of any sign
__device__ __forceinline__ unsigned fenc(float f) {
    unsigned u = __builtin_bit_cast(unsigned, f);
    return u ^ ((u >> 31) ? 0xFFFFFFFFu : 0x80000000u);
}
__device__ __forceinline__ float fdec(unsigned u) {
    u ^= ((u >> 31) ? 0x80000000u : 0xFFFFFFFFu);
    return __builtin_bit_cast(float, u);
}

// ---------------- patch gather (bf16 out) ----------------
__global__ void gather_patches(const float* __restrict__ x, ushortT* __restrict__ patches) {
    int idx = blockIdx.x * 256 + threadIdx.x;          // TPAT*768 total
    if (idx >= TPAT * 768) return;
    int k = idx % 768;
    int t = idx / 768;
    int b = t / NPAT, p = t % NPAT;
    int c = k / 256, r = k % 256;
    int p1 = r / 16, p2 = r % 16;
    int g1 = p / 14, g2 = p % 14;
    patches[idx] = f2bf(x[(((size_t)b * 3 + c) * 224 + (g1 * 16 + p1)) * 224 + (g2 * 16 + p2)]);
}

// ---------------- assemble h = [cls, tok] + pos ----------------
__global__ void assemble_kernel(const float* __restrict__ tok, const float* __restrict__ cls_tok,
                                const float* __restrict__ pos, float* __restrict__ h) {
    int idx = blockIdx.x * 256 + threadIdx.x;          // TTOT*768 exact
    int e = idx % 768;
    int t = idx / 768;
    int b = t / NTOK, n = t % NTOK;
    float v = (n == 0) ? cls_tok[e] : tok[((size_t)(b * NPAT + n - 1)) * 768 + e];
    h[idx] = v + pos[n * 768 + e];
}

// ---------------- fp32 -> bf16 elementwise ----------------
__global__ void cvt_bf16(const float* __restrict__ in, ushortT* __restrict__ out, int n) {
    int idx = blockIdx.x * 256 + threadIdx.x;
    if (idx < n) out[idx] = f2bf(in[idx]);
}

// ---------------- init per-layer gmax slots ----------------
__global__ void init_gmax(unsigned* __restrict__ g) {
    if (threadIdx.x < NLAY) g[threadIdx.x] = 0u;
}

// ---- fp32 [R,C] -> bf16 [C,R] transpose; blockIdx.z = layer (strided) ----
__launch_bounds__(256)
__global__ void transpose_cvt(const float* __restrict__ in, ushortT* __restrict__ out,
                              int R, int Ccol) {
    size_t elems = (size_t)R * Ccol;
    const float* ip = in + (size_t)blockIdx.z * elems;
    ushortT* op = out + (size_t)blockIdx.z * elems;
    __shared__ float tile[32][33];
    int c0 = blockIdx.x * 32, r0 = blockIdx.y * 32;
    int tx = threadIdx.x & 31, ty = threadIdx.x >> 5;
    #pragma unroll
    for (int i = 0; i < 32; i += 8)
        tile[ty + i][tx] = ip[(size_t)(r0 + ty + i) * Ccol + c0 + tx];
    __syncthreads();
    #pragma unroll
    for (int i = 0; i < 32; i += 8)
        op[(size_t)(c0 + ty + i) * R + r0 + tx] = f2bf(tile[tx][ty + i]);
}

// ---------------- bf16 MFMA GEMM, 128x128 tile, BK=32 ----------------
// A [M,K] bf16 (rows padded to tile), Bt [N,K] bf16. fp32 accum.
// EPI: 0 = +bias -> fp32 C; 1 = +bias, gelu -> bf16 Cb
template<int EPI>
__launch_bounds__(256)
__global__ void mgemm(const ushortT* __restrict__ A, const ushortT* __restrict__ Bt,
                      const float* __restrict__ bias, float* __restrict__ C,
                      ushortT* __restrict__ Cb, int M, int N, int K) {
    __shared__ ushortT As[128 * 32];
    __shared__ ushortT Bs[128 * 32];
    const int t = threadIdx.x;
    const int n0 = blockIdx.x * 128;
    const int m0 = blockIdx.y * 128;
    const int lane = t & 63;
    const int wv = t >> 6;
    const int wm = (wv >> 1) * 64;
    const int wn = (wv & 1) * 64;
    f32x4 acc[4][4];
    #pragma unroll
    for (int i = 0; i < 4; ++i)
        #pragma unroll
        for (int j = 0; j < 4; ++j) acc[i][j] = (f32x4)0.f;

    const ushortT* aptr = A + (size_t)(m0 + (t >> 2)) * K + (t & 3) * 8;
    const ushortT* bptr = Bt + (size_t)(n0 + (t >> 2)) * K + (t & 3) * 8;
    ushortT* aLds = As + t * 8;
    ushortT* bLds = Bs + t * 8;
    const size_t rowStep = (size_t)64 * K;

    const int fr = lane & 15;
    const int fko = (lane >> 4) * 8;
    const ushortT* aRd = As + (wm + fr) * 32 + fko;
    const ushortT* bRd = Bs + (wn + fr) * 32 + fko;

    for (int k0 = 0; k0 < K; k0 += 32) {
        load_lds16(aptr, aLds);
        load_lds16(aptr + rowStep, aLds + 2048);
        load_lds16(bptr, bLds);
        load_lds16(bptr + rowStep, bLds + 2048);
        aptr += 32; bptr += 32;
        __syncthreads();
        s16x8 af[4], bfr[4];
        #pragma unroll
        for (int i = 0; i < 4; ++i) af[i] = *(const s16x8*)(aRd + i * 512);
        #pragma unroll
        for (int j = 0; j < 4; ++j) bfr[j] = *(const s16x8*)(bRd + j * 512);
        #pragma unroll
        for (int i = 0; i < 4; ++i)
            #pragma unroll
            for (int j = 0; j < 4; ++j)
                acc[i][j] = __builtin_amdgcn_mfma_f32_16x16x32_bf16(af[i], bfr[j], acc[i][j], 0, 0, 0);
        __syncthreads();
    }

    const int orow = (lane >> 4) * 4;
    const int ocol = lane & 15;
    #pragma unroll
    for (int i = 0; i < 4; ++i) {
        #pragma unroll
        for (int r = 0; r < 4; ++r) {
            int row = m0 + wm + i * 16 + orow + r;
            if (row >= M) continue;
            #pragma unroll
            for (int j = 0; j < 4; ++j) {
                int col = n0 + wn + j * 16 + ocol;
                float v = acc[i][j][r] + bias[col];
                size_t o = (size_t)row * N + col;
                if (EPI == 0) {
                    C[o] = v;
                } else {
                    v = 0.5f * v * (1.0f + erff(v * 0.70710678118f));
                    Cb[o] = f2bf(v);
                }
            }
        }
    }
}

// ---------------- bf16 MFMA GEMM, 64x64 tile, BK=32 (for N=768 W2) ----------------
// EPI here is fixed: +bias, accumulate into fp32 C (residual).
__launch_bounds__(256)
__global__ void mgemm64(const ushortT* __restrict__ A, const ushortT* __restrict__ Bt,
                        const float* __restrict__ bias, float* __restrict__ C,
                        int M, int N, int K) {
    __shared__ ushortT As[64 * 32];
    __shared__ ushortT Bs[64 * 32];
    const int t = threadIdx.x;
    const int n0 = blockIdx.x * 64;
    const int m0 = blockIdx.y * 64;
    const int lane = t & 63;
    const int wv = t >> 6;
    const int wm = (wv >> 1) * 32;
    const int wn = (wv & 1) * 32;
    f32x4 acc[2][2];
    #pragma unroll
    for (int i = 0; i < 2; ++i)
        #pragma unroll
        for (int j = 0; j < 2; ++j) acc[i][j] = (f32x4)0.f;

    const ushortT* aptr = A + (size_t)(m0 + (t >> 2)) * K + (t & 3) * 8;
    const ushortT* bptr = Bt + (size_t)(n0 + (t >> 2)) * K + (t & 3) * 8;
    ushortT* aLds = As + t * 8;
    ushortT* bLds = Bs + t * 8;

    const int fr = lane & 15;
    const int fko = (lane >> 4) * 8;
    const ushortT* aRd = As + (wm + fr) * 32 + fko;
    const ushortT* bRd = Bs + (wn + fr) * 32 + fko;

    for (int k0 = 0; k0 < K; k0 += 32) {
        load_lds16(aptr, aLds);
        load_lds16(bptr, bLds);
        aptr += 32; bptr += 32;
        __syncthreads();
        s16x8 af[2], bfr[2];
        #pragma unroll
        for (int i = 0; i < 2; ++i) af[i] = *(const s16x8*)(aRd + i * 512);
        #pragma unroll
        for (int j = 0; j < 2; ++j) bfr[j] = *(const s16x8*)(bRd + j * 512);
        #pragma unroll
        for (int i = 0; i < 2; ++i)
            #pragma unroll
            for (int j = 0; j < 2; ++j)
                acc[i][j] = __builtin_amdgcn_mfma_f32_16x16x32_bf16(af[i], bfr[j], acc[i][j], 0, 0, 0);
        __syncthreads();
    }

    const int orow = (lane >> 4) * 4;
    const int ocol = lane & 15;
    #pragma unroll
    for (int i = 0; i < 2; ++i) {
        #pragma unroll
        for (int r = 0; r < 4; ++r) {
            int row = m0 + wm + i * 16 + orow + r;
            if (row >= M) continue;
            #pragma unroll
            for (int j = 0; j < 2; ++j) {
                int col = n0 + wn + j * 16 + ocol;
                float v = acc[i][j][r] + bias[col];
                size_t o = (size_t)row * N + col;
                C[o] = C[o] + v;
            }
        }
    }
}

// ---------------- fp32 64x64 tiled GEMM (performer logits) ----------------
// Bt stored [N,K]. epilogue: v = acc*XSCALE - diag[row]
__launch_bounds__(256)
__global__ void gemm64_lg(const float* __restrict__ A, const float* __restrict__ Bm,
                          const float* __restrict__ diag, float* __restrict__ Cd,
                          int Mrows, int Ncols, int Kdim) {
    __shared__ float As[16][64];
    __shared__ float Bs[16][64];
    const int tid = threadIdx.x;
    const int n0 = blockIdx.x * 64;
    const int m0 = blockIdx.y * 64;
    const int tx = tid & 15, ty = tid >> 4;
    float acc[4][4] = {};
    const int lr = tid >> 2;
    const int lc = (tid & 3) << 2;
    for (int k0 = 0; k0 < Kdim; k0 += 16) {
        float4 av = make_float4(0.f, 0.f, 0.f, 0.f);
        int ar = m0 + lr;
        if (ar < Mrows) av = ld4(A + (size_t)ar * Kdim + k0 + lc);
        As[lc + 0][lr] = av.x; As[lc + 1][lr] = av.y;
        As[lc + 2][lr] = av.z; As[lc + 3][lr] = av.w;
        int bn = tid >> 2;
        int bk = (tid & 3) << 2;
        float4 bv = ld4(Bm + (size_t)(n0 + bn) * Kdim + k0 + bk);
        Bs[bk + 0][bn] = bv.x; Bs[bk + 1][bn] = bv.y;
        Bs[bk + 2][bn] = bv.z; Bs[bk + 3][bn] = bv.w;
        __syncthreads();
        #pragma unroll
        for (int k = 0; k < 16; ++k) {
            float a[4], bb[4];
            #pragma unroll
            for (int i = 0; i < 4; ++i) a[i] = As[k][ty * 4 + i];
            #pragma unroll
            for (int j = 0; j < 4; ++j) bb[j] = Bs[k][tx * 4 + j];
            #pragma unroll
            for (int i = 0; i < 4; ++i)
                #pragma unroll
                for (int j = 0; j < 4; ++j)
                    acc[i][j] += a[i] * bb[j];
        }
        __syncthreads();
    }
    #pragma unroll
    for (int i = 0; i < 4; ++i) {
        int row = m0 + ty * 4 + i;
        if (row >= Mrows) continue;
        #pragma unroll
        for (int j = 0; j < 4; ++j) {
            int col = n0 + tx * 4 + j;
            Cd[(size_t)row * Ncols + col] = acc[i][j] * XSCALE - diag[row];
        }
    }
}

// ---------------- LayerNorm: fp32 out + optional bf16 out + optional diag ----------------
__launch_bounds__(256)
__global__ void ln_kernel(const float* __restrict__ in, int rowStride,
                          const float* __restrict__ g, const float* __restrict__ b,
                          float* __restrict__ out, ushortT* __restrict__ outb,
                          float* __restrict__ diag) {
    int row = blockIdx.x;
    const float* xr = in + (size_t)row * rowStride;
    int tid = threadIdx.x;
    float v0 = xr[tid], v1 = xr[tid + 256], v2 = xr[tid + 512];
    float s = v0 + v1 + v2;
    float q = v0 * v0 + v1 * v1 + v2 * v2;
    int lane = tid & 63, wid = tid >> 6;
    #pragma unroll
    for (int off = 32; off >= 1; off >>= 1) {
        s += __shfl_down(s, off);
        q += __shfl_down(q, off);
    }
    __shared__ float sh[8];
    __shared__ float mu_s, rs_s;
    if (lane == 0) { sh[wid] = s; sh[4 + wid] = q; }
    __syncthreads();
    if (tid == 0) {
        float ts = sh[0] + sh[1] + sh[2] + sh[3];
        float tq = sh[4] + sh[5] + sh[6] + sh[7];
        float mu = ts * (1.0f / 768.0f);
        float var = tq * (1.0f / 768.0f) - mu * mu;
        mu_s = mu;
        rs_s = rsqrtf(var + 1e-5f);
    }
    __syncthreads();
    float mu = mu_s, rs = rs_s;
    float y0 = (v0 - mu) * rs * g[tid] + b[tid];
    float y1 = (v1 - mu) * rs * g[tid + 256] + b[tid + 256];
    float y2 = (v2 - mu) * rs * g[tid + 512] + b[tid + 512];
    size_t o = (size_t)row * 768;
    out[o + tid] = y0;
    out[o + tid + 256] = y1;
    out[o + tid + 512] = y2;
    if (outb) {
        outb[o + tid] = f2bf(y0);
        outb[o + tid + 256] = f2bf(y1);
        outb[o + tid + 512] = f2bf(y2);
    }
    if (diag) {
        float qq = y0 * y0 + y1 * y1 + y2 * y2;
        #pragma unroll
        for (int off = 32; off >= 1; off >>= 1) qq += __shfl_down(qq, off);
        if (lane == 0) sh[wid] = qq;
        __syncthreads();
        if (tid == 0) diag[row] = 0.5f * XSCALE * XSCALE * (sh[0] + sh[1] + sh[2] + sh[3]);
    }
}

// ---------------- row max + qf + per-layer global max (atomic) ----------------
__launch_bounds__(256)
__global__ void rowqf_kernel(const float* __restrict__ lg, float* __restrict__ qf,
                             unsigned* __restrict__ gslot) {
    int row = blockIdx.x;
    int tid = threadIdx.x;
    float v = lg[(size_t)row * 256 + tid];
    float m = v;
    int lane = tid & 63, wid = tid >> 6;
    #pragma unroll
    for (int off = 32; off >= 1; off >>= 1) m = fmaxf(m, __shfl_down(m, off));
    __shared__ float sh[4];
    __shared__ float bm_s;
    if (lane == 0) sh[wid] = m;
    __syncthreads();
    if (tid == 0) {
        float bm = fmaxf(fmaxf(sh[0], sh[1]), fmaxf(sh[2], sh[3]));
        bm_s = bm;
        atomicMax(gslot, fenc(bm));
    }
    __syncthreads();
    qf[(size_t)row * 256 + tid] = expf(v - bm_s) * 0.0625f + 1e-4f;
}

// ---- kv[b,m,e] = sum_n kf[b,n,m]*xln[b,n,e]; kf computed inline; ksum[b,m] ----
__launch_bounds__(256)
__global__ void kv_kernel(const float* __restrict__ lg, const unsigned* __restrict__ gslot,
                          const float* __restrict__ xln,
                          float* __restrict__ kv, float* __restrict__ ksum) {
    int blk = blockIdx.x;            // BSZ*32
    int b = blk >> 5;
    int m0 = (blk & 31) << 3;        // 8 m's per block
    __shared__ float kc[NTOK * 8];
    int tid = threadIdx.x;
    float gm = fdec(*gslot);
    for (int i = tid; i < NTOK * 8; i += 256) {
        int n = i >> 3, j = i & 7;
        float lv = lg[((size_t)(b * NTOK + n)) * 256 + m0 + j];
        kc[i] = expf(lv - gm) * 0.0625f + 1e-4f;
    }
    __syncthreads();
    if (tid < 8) {
        float s = 0.f;
        for (int n = 0; n < NTOK; ++n) s += kc[n * 8 + tid];
        ksum[b * 256 + m0 + tid] = s;
    }
    float acc[8][3] = {};
    const float* xb = xln + (size_t)b * NTOK * 768;
    for (int n = 0; n < NTOK; ++n) {
        float x0 = xb[n * 768 + tid];
        float x1 = xb[n * 768 + tid + 256];
        float x2 = xb[n * 768 + tid + 512];
        #pragma unroll
        for (int j = 0; j < 8; ++j) {
            float kk = kc[n * 8 + j];
            acc[j][0] += kk * x0;
            acc[j][1] += kk * x1;
            acc[j][2] += kk * x2;
        }
    }
    float* kvb = kv + ((size_t)b * 256 + m0) * 768;
    #pragma unroll
    for (int j = 0; j < 8; ++j) {
        kvb[j * 768 + tid] = acc[j][0];
        kvb[j * 768 + tid + 256] = acc[j][1];
        kvb[j * 768 + tid + 512] = acc[j][2];
    }
}

// ---- att + residual + fused LN2: h += (qf@kv)/den; xlnbf = LN(h) ----
__launch_bounds__(256)
__global__ void att_ln2(const float* __restrict__ qf, const float* __restrict__ ksum,
                        const float* __restrict__ kv, float* __restrict__ h,
                        const float* __restrict__ lng, const float* __restrict__ lnb,
                        ushortT* __restrict__ xlnbf) {
    int blk = blockIdx.x;            // BSZ*25
    int b = blk / 25;
    int n0 = (blk % 25) * 8;
    int nrows = NTOK - n0; if (nrows > 8) nrows = 8;
    __shared__ float qs[8][256];
    __shared__ float dinv[8];
    __shared__ float sh[8];
    __shared__ float mu_s, rs_s;
    int tid = threadIdx.x;
    for (int r = 0; r < nrows; ++r)
        qs[r][tid] = qf[((size_t)(b * NTOK + n0 + r)) * 256 + tid];
    for (int r = nrows; r < 8; ++r) qs[r][tid] = 0.f;
    __syncthreads();
    int lane = tid & 63, wid = tid >> 6;
    float ks = ksum[b * 256 + tid];
    for (int r = 0; r < nrows; ++r) {
        float d = qs[r][tid] * ks;
        #pragma unroll
        for (int off = 32; off >= 1; off >>= 1) d += __shfl_down(d, off);
        if (lane == 0) sh[wid] = d;
        __syncthreads();
        if (tid == 0) dinv[r] = 1.0f / (sh[0] + sh[1] + sh[2] + sh[3]);
        __syncthreads();
    }
    float acc[8][3] = {};
    const float* kvb = kv + (size_t)b * 256 * 768;
    for (int m = 0; m < 256; ++m) {
        float k0 = kvb[m * 768 + tid];
        float k1 = kvb[m * 768 + tid + 256];
        float k2 = kvb[m * 768 + tid + 512];
        #pragma unroll
        for (int r = 0; r < 8; ++r) {
            float qv = qs[r][m];
            acc[r][0] += qv * k0;
            acc[r][1] += qv * k1;
            acc[r][2] += qv * k2;
        }
    }
    float g0 = lng[tid], g1 = lng[tid + 256], g2 = lng[tid + 512];
    float c0 = lnb[tid], c1 = lnb[tid + 256], c2 = lnb[tid + 512];
    for (int r = 0; r < nrows; ++r) {
        float di = dinv[r];
        size_t o = ((size_t)(b * NTOK + n0 + r)) * 768;
        float h0 = h[o + tid]       + acc[r][0] * di;
        float h1 = h[o + tid + 256] + acc[r][1] * di;
        float h2 = h[o + tid + 512] + acc[r][2] * di;
        h[o + tid] = h0; h[o + tid + 256] = h1; h[o + tid + 512] = h2;
        float s = h0 + h1 + h2;
        float q = h0 * h0 + h1 * h1 + h2 * h2;
        #pragma unroll
        for (int off = 32; off >= 1; off >>= 1) {
            s += __shfl_down(s, off);
            q += __shfl_down(q, off);
        }
        if (lane == 0) { sh[wid] = s; sh[4 + wid] = q; }
        __syncthreads();
        if (tid == 0) {
            float ts = sh[0] + sh[1] + sh[2] + sh[3];
            float tq = sh[4] + sh[5] + sh[6] + sh[7];
            float mu = ts * (1.0f / 768.0f);
            mu_s = mu;
            rs_s = rsqrtf(tq * (1.0f / 768.0f) - mu * mu + 1e-5f);
        }
        __syncthreads();
        float mu = mu_s, rs = rs_s;
        xlnbf[o + tid]       = f2bf((h0 - mu) * rs * g0 + c0);
        xlnbf[o + tid + 256] = f2bf((h1 - mu) * rs * g1 + c1);
        xlnbf[o + tid + 512] = f2bf((h2 - mu) * rs * g2 + c2);
    }
}

// ---------------- classifier head ----------------
__global__ void head_kernel(const float* __restrict__ cls, const float* __restrict__ w,
                            const float* __restrict__ hb, float* __restrict__ out) {
    int idx = blockIdx.x * 256 + threadIdx.x;
    if (idx >= BSZ * NCLS) return;
    int i = idx / NCLS, j = idx % NCLS;
    float acc = hb[j];
    const float* cr = cls + (size_t)i * 768;
    for (int k = 0; k < 768; ++k) acc += cr[k] * w[k * NCLS + j];
    out[idx] = acc;
}

extern "C" void kernel_launch(void* const* d_in, const int* in_sizes, int n_in,
                              void* d_out, int out_size, void* d_ws, size_t ws_size,
                              hipStream_t stream) {
    const float* x       = (const float*)d_in[0];
    const float* cls_tok = (const float*)d_in[1];
    const float* pos_emb = (const float*)d_in[2];
    const float* patch_w = (const float*)d_in[3];
    const float* patch_b = (const float*)d_in[4];
    const float* ln1_g   = (const float*)d_in[5];
    const float* ln1_b   = (const float*)d_in[6];
    const float* proj    = (const float*)d_in[7];
    const float* ln2_g   = (const float*)d_in[8];
    const float* ln2_b   = (const float*)d_in[9];
    const float* w1      = (const float*)d_in[10];
    const float* b1      = (const float*)d_in[11];
    const float* w2      = (const float*)d_in[12];
    const float* b2      = (const float*)d_in[13];
    const float* lnf_g   = (const float*)d_in[14];
    const float* lnf_b   = (const float*)d_in[15];
    const float* head_w  = (const float*)d_in[16];
    const float* head_b  = (const float*)d_in[17];
    float* out = (float*)d_out;

    char* wsb = (char*)d_ws;
    // region A (aliased): y1b [3200x3072 bf16] in loop; pre-loop: tok fp32 + patches bf16
    ushortT* y1b        = (ushortT*)wsb;                       // 19,660,800 B
    float*   tok        = (float*)wsb;                         // 9,633,792 B
    ushortT* patches_bf = (ushortT*)(wsb + 9633792);           // 4,915,200 B
    size_t off = 19660800;
    float*    h      = (float*)(wsb + off);    off += 9682944;   // [3152,768]
    float*    xln    = (float*)(wsb + off);    off += 9830400;   // [3200,768] fp32
    ushortT*  xln_bf = (ushortT*)(wsb + off);  off += 4915200;   // [3200,768] bf16
    float*    lg     = (float*)(wsb + off);    off += 3227648;   // [3152,256]
    float*    qf     = (float*)(wsb + off);    off += 3227648;
    float*    kv     = (float*)(wsb + off);    off += 12582912;  // [16,256,768]
    ushortT*  pwb    = (ushortT*)(wsb + off);  off += 1179648;   // [768,768] bf16
    float*    diag   = (float*)(wsb + off);    off += 12800;
    unsigned* gml    = (unsigned*)(wsb + off); off += 256;       // per-layer global max (encoded)
    float*    ksum   = (float*)(wsb + off);    off += 16384;
    float*    clsln  = (float*)(wsb + off);    off += 49152;
    const size_t WSTRIDE = (size_t)3072 * 768; // elements per layer weight
    ushortT*  w1t    = (ushortT*)(wsb + off);
    bool big = ws_size >= off + 2u * NLAY * WSTRIDE * sizeof(ushortT);
    size_t w1bytes = (big ? NLAY : 1) * WSTRIDE * sizeof(ushortT);
    ushortT*  w2t    = (ushortT*)(wsb + off + w1bytes);

    init_gmax<<<1, 64, 0, stream>>>(gml);

    // --- batched weight conversion (all layers upfront when ws allows) ---
    if (big) {
        transpose_cvt<<<dim3(96, 24, NLAY), 256, 0, stream>>>(w1, w1t, 768, FDIM);
        transpose_cvt<<<dim3(24, 96, NLAY), 256, 0, stream>>>(w2, w2t, FDIM, 768);
    }

    // --- patch embedding (bf16 MFMA) ---
    gather_patches<<<9408, 256, 0, stream>>>(x, patches_bf);
    cvt_bf16<<<2304, 256, 0, stream>>>(patch_w, pwb, 768 * 768);
    mgemm<0><<<dim3(6, 25), 256, 0, stream>>>(patches_bf, pwb, patch_b, tok, nullptr,
                                              TPAT, 768, 768);
    assemble_kernel<<<9456, 256, 0, stream>>>(tok, cls_tok, pos_emb, h);

    // --- transformer layers ---
    for (int l = 0; l < NLAY; ++l) {
        ushortT* w1l = big ? w1t + (size_t)l * WSTRIDE : w1t;
        ushortT* w2l = big ? w2t + (size_t)l * WSTRIDE : w2t;
        if (!big) {
            transpose_cvt<<<dim3(96, 24), 256, 0, stream>>>(w1 + (size_t)l * WSTRIDE, w1l, 768, FDIM);
            transpose_cvt<<<dim3(24, 96), 256, 0, stream>>>(w2 + (size_t)l * WSTRIDE, w2l, FDIM, 768);
        }

        ln_kernel<<<TTOT, 256, 0, stream>>>(h, 768, ln1_g + l * 768, ln1_b + l * 768,
                                            xln, nullptr, diag);
        gemm64_lg<<<dim3(4, 50), 256, 0, stream>>>(xln, proj + (size_t)l * 256 * 768,
                                                   diag, lg, TTOT, 256, 768);
        rowqf_kernel<<<TTOT, 256, 0, stream>>>(lg, qf, gml + l);
        kv_kernel<<<BSZ * 32, 256, 0, stream>>>(lg, gml + l, xln, kv, ksum);
        att_ln2<<<BSZ * 25, 256, 0, stream>>>(qf, ksum, kv, h,
                                              ln2_g + l * 768, ln2_b + l * 768, xln_bf);
        mgemm<1><<<dim3(24, 25), 256, 0, stream>>>(xln_bf, w1l, b1 + l * FDIM,
                                                   nullptr, y1b, TTOT, FDIM, 768);
        mgemm64<<<dim3(12, 50), 256, 0, stream>>>(y1b, w2l, b2 + l * 768,
                                                  h, TTOT, 768, FDIM);
    }

    // --- final LN on cls tokens + head ---
    ln_kernel<<<BSZ, 256, 0, stream>>>(h, NTOK * 768, lnf_g, lnf_b, clsln, nullptr, nullptr);
    head_kernel<<<(BSZ * NCLS + 255) / 256, 256, 0, stream>>>(clsln, head_w, head_b, out);
}

// Round 4
// 3186.148 us; speedup vs baseline: 2.5722x; 1.1582x over previous
//
#include <hip/hip_runtime.h>
#include <math.h>

#define BSZ   16
#define NTOK  197
#define NPAT  196
#define EDIM  768
#define MDIM  256
#define FDIM  3072
#define NLAY  12
#define NCLS  1000
#define TTOT  (BSZ*NTOK)   // 3152
#define TPAT  (BSZ*NPAT)   // 3136
#define XSCALE 0.18995893f // 768^-0.25

typedef unsigned short ushortT;
typedef short s16x8 __attribute__((ext_vector_type(8)));
typedef float f32x4 __attribute__((ext_vector_type(4)));

__device__ __forceinline__ float4 ld4(const float* p) {
    return *reinterpret_cast<const float4*>(p);
}
__device__ __forceinline__ ushortT f2bf(float f) {
    unsigned u = __builtin_bit_cast(unsigned, f);
    unsigned r = (u + 0x7fff + ((u >> 16) & 1)) >> 16;
    return (ushortT)r;
}
__device__ __forceinline__ void load_lds16(const ushortT* g, ushortT* lds) {
    __builtin_amdgcn_global_load_lds(
        (const __attribute__((address_space(1))) unsigned int*)g,
        (__attribute__((address_space(3))) unsigned int*)lds, 16, 0, 0);
}
// order-preserving float<->uint encoding for atomicMax over floats of any sign
__device__ __forceinline__ unsigned fenc(float f) {
    unsigned u = __builtin_bit_cast(unsigned, f);
    return u ^ ((u >> 31) ? 0xFFFFFFFFu : 0x80000000u);
}
__device__ __forceinline__ float fdec(unsigned u) {
    u ^= ((u >> 31) ? 0x80000000u : 0xFFFFFFFFu);
    return __builtin_bit_cast(float, u);
}

// ---------------- patch gather (bf16 out) ----------------
__global__ void gather_patches(const float* __restrict__ x, ushortT* __restrict__ patches) {
    int idx = blockIdx.x * 256 + threadIdx.x;          // TPAT*768 total
    if (idx >= TPAT * 768) return;
    int k = idx % 768;
    int t = idx / 768;
    int b = t / NPAT, p = t % NPAT;
    int c = k / 256, r = k % 256;
    int p1 = r / 16, p2 = r % 16;
    int g1 = p / 14, g2 = p % 14;
    patches[idx] = f2bf(x[(((size_t)b * 3 + c) * 224 + (g1 * 16 + p1)) * 224 + (g2 * 16 + p2)]);
}

// ---------------- assemble h = [cls, tok] + pos ----------------
__global__ void assemble_kernel(const float* __restrict__ tok, const float* __restrict__ cls_tok,
                                const float* __restrict__ pos, float* __restrict__ h) {
    int idx = blockIdx.x * 256 + threadIdx.x;          // TTOT*768 exact
    int e = idx % 768;
    int t = idx / 768;
    int b = t / NTOK, n = t % NTOK;
    float v = (n == 0) ? cls_tok[e] : tok[((size_t)(b * NPAT + n - 1)) * 768 + e];
    h[idx] = v + pos[n * 768 + e];
}

// ---------------- fp32 -> bf16 elementwise ----------------
__global__ void cvt_bf16(const float* __restrict__ in, ushortT* __restrict__ out, int n) {
    int idx = blockIdx.x * 256 + threadIdx.x;
    if (idx < n) out[idx] = f2bf(in[idx]);
}

// ---------------- init per-layer gmax slots ----------------
__global__ void init_gmax(unsigned* __restrict__ g) {
    if (threadIdx.x < NLAY) g[threadIdx.x] = 0u;
}

// ---- fp32 [R,C] -> bf16 [C,R] transpose; blockIdx.z = layer (strided) ----
__launch_bounds__(256)
__global__ void transpose_cvt(const float* __restrict__ in, ushortT* __restrict__ out,
                              int R, int Ccol) {
    size_t elems = (size_t)R * Ccol;
    const float* ip = in + (size_t)blockIdx.z * elems;
    ushortT* op = out + (size_t)blockIdx.z * elems;
    __shared__ float tile[32][33];
    int c0 = blockIdx.x * 32, r0 = blockIdx.y * 32;
    int tx = threadIdx.x & 31, ty = threadIdx.x >> 5;
    #pragma unroll
    for (int i = 0; i < 32; i += 8)
        tile[ty + i][tx] = ip[(size_t)(r0 + ty + i) * Ccol + c0 + tx];
    __syncthreads();
    #pragma unroll
    for (int i = 0; i < 32; i += 8)
        op[(size_t)(c0 + ty + i) * R + r0 + tx] = f2bf(tile[tx][ty + i]);
}

// ---------------- bf16 MFMA GEMM, 128x128 tile, BK=32 ----------------
// A [M,K] bf16 (rows padded to tile), Bt [N,K] bf16. fp32 accum.
// EPI 1: +bias, gelu -> bf16 Cb   (used for W1)
__launch_bounds__(256)
__global__ void mgemm128_gelu(const ushortT* __restrict__ A, const ushortT* __restrict__ Bt,
                              const float* __restrict__ bias, ushortT* __restrict__ Cb,
                              int M, int N, int K) {
    __shared__ ushortT As[128 * 32];
    __shared__ ushortT Bs[128 * 32];
    const int t = threadIdx.x;
    const int n0 = blockIdx.x * 128;
    const int m0 = blockIdx.y * 128;
    const int lane = t & 63;
    const int wv = t >> 6;
    const int wm = (wv >> 1) * 64;
    const int wn = (wv & 1) * 64;
    f32x4 acc[4][4];
    #pragma unroll
    for (int i = 0; i < 4; ++i)
        #pragma unroll
        for (int j = 0; j < 4; ++j) acc[i][j] = (f32x4)0.f;

    const ushortT* aptr = A + (size_t)(m0 + (t >> 2)) * K + (t & 3) * 8;
    const ushortT* bptr = Bt + (size_t)(n0 + (t >> 2)) * K + (t & 3) * 8;
    ushortT* aLds = As + t * 8;
    ushortT* bLds = Bs + t * 8;
    const size_t rowStep = (size_t)64 * K;

    const int fr = lane & 15;
    const int fko = (lane >> 4) * 8;
    const ushortT* aRd = As + (wm + fr) * 32 + fko;
    const ushortT* bRd = Bs + (wn + fr) * 32 + fko;

    for (int k0 = 0; k0 < K; k0 += 32) {
        load_lds16(aptr, aLds);
        load_lds16(aptr + rowStep, aLds + 2048);
        load_lds16(bptr, bLds);
        load_lds16(bptr + rowStep, bLds + 2048);
        aptr += 32; bptr += 32;
        __syncthreads();
        s16x8 af[4], bfr[4];
        #pragma unroll
        for (int i = 0; i < 4; ++i) af[i] = *(const s16x8*)(aRd + i * 512);
        #pragma unroll
        for (int j = 0; j < 4; ++j) bfr[j] = *(const s16x8*)(bRd + j * 512);
        #pragma unroll
        for (int i = 0; i < 4; ++i)
            #pragma unroll
            for (int j = 0; j < 4; ++j)
                acc[i][j] = __builtin_amdgcn_mfma_f32_16x16x32_bf16(af[i], bfr[j], acc[i][j], 0, 0, 0);
        __syncthreads();
    }

    const int orow = (lane >> 4) * 4;
    const int ocol = lane & 15;
    #pragma unroll
    for (int i = 0; i < 4; ++i) {
        #pragma unroll
        for (int r = 0; r < 4; ++r) {
            int row = m0 + wm + i * 16 + orow + r;
            if (row >= M) continue;
            #pragma unroll
            for (int j = 0; j < 4; ++j) {
                int col = n0 + wn + j * 16 + ocol;
                float v = acc[i][j][r] + bias[col];
                v = 0.5f * v * (1.0f + erff(v * 0.70710678118f));
                Cb[(size_t)row * N + col] = f2bf(v);
            }
        }
    }
}

// ---------------- bf16 MFMA GEMM, 64x64 tile, BK=32 ----------------
// EPI: 0 = +bias -> fp32 C (patch embed); 2 = +bias, += C (W2 residual);
//      3 = v*XSCALE - diag[row] -> fp32 C (performer logits)
template<int EPI>
__launch_bounds__(256)
__global__ void mgemm64(const ushortT* __restrict__ A, const ushortT* __restrict__ Bt,
                        const float* __restrict__ bias, const float* __restrict__ diag,
                        float* __restrict__ C, int M, int N, int K) {
    __shared__ ushortT As[64 * 32];
    __shared__ ushortT Bs[64 * 32];
    const int t = threadIdx.x;
    const int n0 = blockIdx.x * 64;
    const int m0 = blockIdx.y * 64;
    const int lane = t & 63;
    const int wv = t >> 6;
    const int wm = (wv >> 1) * 32;
    const int wn = (wv & 1) * 32;
    f32x4 acc[2][2];
    #pragma unroll
    for (int i = 0; i < 2; ++i)
        #pragma unroll
        for (int j = 0; j < 2; ++j) acc[i][j] = (f32x4)0.f;

    const ushortT* aptr = A + (size_t)(m0 + (t >> 2)) * K + (t & 3) * 8;
    const ushortT* bptr = Bt + (size_t)(n0 + (t >> 2)) * K + (t & 3) * 8;
    ushortT* aLds = As + t * 8;
    ushortT* bLds = Bs + t * 8;

    const int fr = lane & 15;
    const int fko = (lane >> 4) * 8;
    const ushortT* aRd = As + (wm + fr) * 32 + fko;
    const ushortT* bRd = Bs + (wn + fr) * 32 + fko;

    for (int k0 = 0; k0 < K; k0 += 32) {
        load_lds16(aptr, aLds);
        load_lds16(bptr, bLds);
        aptr += 32; bptr += 32;
        __syncthreads();
        s16x8 af[2], bfr[2];
        #pragma unroll
        for (int i = 0; i < 2; ++i) af[i] = *(const s16x8*)(aRd + i * 512);
        #pragma unroll
        for (int j = 0; j < 2; ++j) bfr[j] = *(const s16x8*)(bRd + j * 512);
        #pragma unroll
        for (int i = 0; i < 2; ++i)
            #pragma unroll
            for (int j = 0; j < 2; ++j)
                acc[i][j] = __builtin_amdgcn_mfma_f32_16x16x32_bf16(af[i], bfr[j], acc[i][j], 0, 0, 0);
        __syncthreads();
    }

    const int orow = (lane >> 4) * 4;
    const int ocol = lane & 15;
    #pragma unroll
    for (int i = 0; i < 2; ++i) {
        #pragma unroll
        for (int r = 0; r < 4; ++r) {
            int row = m0 + wm + i * 16 + orow + r;
            if (row >= M) continue;
            #pragma unroll
            for (int j = 0; j < 2; ++j) {
                int col = n0 + wn + j * 16 + ocol;
                float v = acc[i][j][r];
                size_t o = (size_t)row * N + col;
                if (EPI == 0) {
                    C[o] = v + bias[col];
                } else if (EPI == 2) {
                    C[o] = C[o] + v + bias[col];
                } else {
                    C[o] = v * XSCALE - diag[row];
                }
            }
        }
    }
}

// ---------------- LayerNorm: fp32 out + optional bf16 out + optional diag ----------------
__launch_bounds__(256)
__global__ void ln_kernel(const float* __restrict__ in, int rowStride,
                          const float* __restrict__ g, const float* __restrict__ b,
                          float* __restrict__ out, ushortT* __restrict__ outb,
                          float* __restrict__ diag) {
    int row = blockIdx.x;
    const float* xr = in + (size_t)row * rowStride;
    int tid = threadIdx.x;
    float v0 = xr[tid], v1 = xr[tid + 256], v2 = xr[tid + 512];
    float s = v0 + v1 + v2;
    float q = v0 * v0 + v1 * v1 + v2 * v2;
    int lane = tid & 63, wid = tid >> 6;
    #pragma unroll
    for (int off = 32; off >= 1; off >>= 1) {
        s += __shfl_down(s, off);
        q += __shfl_down(q, off);
    }
    __shared__ float sh[8];
    __shared__ float mu_s, rs_s;
    if (lane == 0) { sh[wid] = s; sh[4 + wid] = q; }
    __syncthreads();
    if (tid == 0) {
        float ts = sh[0] + sh[1] + sh[2] + sh[3];
        float tq = sh[4] + sh[5] + sh[6] + sh[7];
        float mu = ts * (1.0f / 768.0f);
        float var = tq * (1.0f / 768.0f) - mu * mu;
        mu_s = mu;
        rs_s = rsqrtf(var + 1e-5f);
    }
    __syncthreads();
    float mu = mu_s, rs = rs_s;
    float y0 = (v0 - mu) * rs * g[tid] + b[tid];
    float y1 = (v1 - mu) * rs * g[tid + 256] + b[tid + 256];
    float y2 = (v2 - mu) * rs * g[tid + 512] + b[tid + 512];
    size_t o = (size_t)row * 768;
    out[o + tid] = y0;
    out[o + tid + 256] = y1;
    out[o + tid + 512] = y2;
    if (outb) {
        outb[o + tid] = f2bf(y0);
        outb[o + tid + 256] = f2bf(y1);
        outb[o + tid + 512] = f2bf(y2);
    }
    if (diag) {
        float qq = y0 * y0 + y1 * y1 + y2 * y2;
        #pragma unroll
        for (int off = 32; off >= 1; off >>= 1) qq += __shfl_down(qq, off);
        if (lane == 0) sh[wid] = qq;
        __syncthreads();
        if (tid == 0) diag[row] = 0.5f * XSCALE * XSCALE * (sh[0] + sh[1] + sh[2] + sh[3]);
    }
}

// ---------------- row max + qf + per-layer global max (atomic) ----------------
__launch_bounds__(256)
__global__ void rowqf_kernel(const float* __restrict__ lg, float* __restrict__ qf,
                             unsigned* __restrict__ gslot) {
    int row = blockIdx.x;
    int tid = threadIdx.x;
    float v = lg[(size_t)row * 256 + tid];
    float m = v;
    int lane = tid & 63, wid = tid >> 6;
    #pragma unroll
    for (int off = 32; off >= 1; off >>= 1) m = fmaxf(m, __shfl_down(m, off));
    __shared__ float sh[4];
    __shared__ float bm_s;
    if (lane == 0) sh[wid] = m;
    __syncthreads();
    if (tid == 0) {
        float bm = fmaxf(fmaxf(sh[0], sh[1]), fmaxf(sh[2], sh[3]));
        bm_s = bm;
        atomicMax(gslot, fenc(bm));
    }
    __syncthreads();
    qf[(size_t)row * 256 + tid] = expf(v - bm_s) * 0.0625f + 1e-4f;
}

// ---- kv[b,m,e] = sum_n kf[b,n,m]*xln[b,n,e]; kf computed inline; ksum[b,m] ----
__launch_bounds__(256)
__global__ void kv_kernel(const float* __restrict__ lg, const unsigned* __restrict__ gslot,
                          const float* __restrict__ xln,
                          float* __restrict__ kv, float* __restrict__ ksum) {
    int blk = blockIdx.x;            // BSZ*32
    int b = blk >> 5;
    int m0 = (blk & 31) << 3;        // 8 m's per block
    __shared__ float kc[NTOK * 8];
    int tid = threadIdx.x;
    float gm = fdec(*gslot);
    for (int i = tid; i < NTOK * 8; i += 256) {
        int n = i >> 3, j = i & 7;
        float lv = lg[((size_t)(b * NTOK + n)) * 256 + m0 + j];
        kc[i] = expf(lv - gm) * 0.0625f + 1e-4f;
    }
    __syncthreads();
    if (tid < 8) {
        float s = 0.f;
        for (int n = 0; n < NTOK; ++n) s += kc[n * 8 + tid];
        ksum[b * 256 + m0 + tid] = s;
    }
    float acc[8][3] = {};
    const float* xb = xln + (size_t)b * NTOK * 768;
    for (int n = 0; n < NTOK; ++n) {
        float x0 = xb[n * 768 + tid];
        float x1 = xb[n * 768 + tid + 256];
        float x2 = xb[n * 768 + tid + 512];
        #pragma unroll
        for (int j = 0; j < 8; ++j) {
            float kk = kc[n * 8 + j];
            acc[j][0] += kk * x0;
            acc[j][1] += kk * x1;
            acc[j][2] += kk * x2;
        }
    }
    float* kvb = kv + ((size_t)b * 256 + m0) * 768;
    #pragma unroll
    for (int j = 0; j < 8; ++j) {
        kvb[j * 768 + tid] = acc[j][0];
        kvb[j * 768 + tid + 256] = acc[j][1];
        kvb[j * 768 + tid + 512] = acc[j][2];
    }
}

// ---- att + residual + fused LN2: h += (qf@kv)/den; xlnbf = LN(h) ----
// wave-parallel reductions: 4 barriers total (was 16+)
__launch_bounds__(256)
__global__ void att_ln2(const float* __restrict__ qf, const float* __restrict__ ksum,
                        const float* __restrict__ kv, float* __restrict__ h,
                        const float* __restrict__ lng, const float* __restrict__ lnb,
                        ushortT* __restrict__ xlnbf) {
    int blk = blockIdx.x;            // BSZ*25
    int b = blk / 25;
    int n0 = (blk % 25) * 8;
    int nrows = NTOK - n0; if (nrows > 8) nrows = 8;
    __shared__ float qs[8][256];
    __shared__ float redA[8][4];
    __shared__ float redB[8][4];
    __shared__ float dinv[8];
    __shared__ float mu8[8], rs8[8];
    int tid = threadIdx.x;
    int lane = tid & 63, wid = tid >> 6;
    #pragma unroll
    for (int r = 0; r < 8; ++r)
        qs[r][tid] = (r < nrows) ? qf[((size_t)(b * NTOK + n0 + r)) * 256 + tid] : 0.f;
    __syncthreads();
    // den for all 8 rows, wave-parallel
    float ks = ksum[b * 256 + tid];
    #pragma unroll
    for (int r = 0; r < 8; ++r) {
        float d = qs[r][tid] * ks;
        #pragma unroll
        for (int off = 32; off >= 1; off >>= 1) d += __shfl_down(d, off);
        if (lane == 0) redA[r][wid] = d;
    }
    __syncthreads();
    if (tid < 8) {
        float d = redA[tid][0] + redA[tid][1] + redA[tid][2] + redA[tid][3];
        dinv[tid] = 1.0f / d;
    }
    __syncthreads();
    // numerator: acc over m
    float acc[8][3] = {};
    const float* kvb = kv + (size_t)b * 256 * 768;
    for (int m = 0; m < 256; ++m) {
        float k0 = kvb[m * 768 + tid];
        float k1 = kvb[m * 768 + tid + 256];
        float k2 = kvb[m * 768 + tid + 512];
        #pragma unroll
        for (int r = 0; r < 8; ++r) {
            float qv = qs[r][m];
            acc[r][0] += qv * k0;
            acc[r][1] += qv * k1;
            acc[r][2] += qv * k2;
        }
    }
    // h update + LN partials (all rows), wave-parallel reductions
    float hv[8][3];
    #pragma unroll
    for (int r = 0; r < 8; ++r) {
        float ps = 0.f, pq = 0.f;
        if (r < nrows) {
            float di = dinv[r];
            size_t o = ((size_t)(b * NTOK + n0 + r)) * 768;
            float h0 = h[o + tid]       + acc[r][0] * di;
            float h1 = h[o + tid + 256] + acc[r][1] * di;
            float h2 = h[o + tid + 512] + acc[r][2] * di;
            h[o + tid] = h0; h[o + tid + 256] = h1; h[o + tid + 512] = h2;
            hv[r][0] = h0; hv[r][1] = h1; hv[r][2] = h2;
            ps = h0 + h1 + h2;
            pq = h0 * h0 + h1 * h1 + h2 * h2;
        }
        #pragma unroll
        for (int off = 32; off >= 1; off >>= 1) {
            ps += __shfl_down(ps, off);
            pq += __shfl_down(pq, off);
        }
        if (lane == 0) { redA[r][wid] = ps; redB[r][wid] = pq; }
    }
    __syncthreads();
    if (tid < 8) {
        float ts = redA[tid][0] + redA[tid][1] + redA[tid][2] + redA[tid][3];
        float tq = redB[tid][0] + redB[tid][1] + redB[tid][2] + redB[tid][3];
        float mu = ts * (1.0f / 768.0f);
        mu8[tid] = mu;
        rs8[tid] = rsqrtf(tq * (1.0f / 768.0f) - mu * mu + 1e-5f);
    }
    __syncthreads();
    float g0 = lng[tid], g1 = lng[tid + 256], g2 = lng[tid + 512];
    float c0 = lnb[tid], c1 = lnb[tid + 256], c2 = lnb[tid + 512];
    for (int r = 0; r < nrows; ++r) {
        float mu = mu8[r], rs = rs8[r];
        size_t o = ((size_t)(b * NTOK + n0 + r)) * 768;
        xlnbf[o + tid]       = f2bf((hv[r][0] - mu) * rs * g0 + c0);
        xlnbf[o + tid + 256] = f2bf((hv[r][1] - mu) * rs * g1 + c1);
        xlnbf[o + tid + 512] = f2bf((hv[r][2] - mu) * rs * g2 + c2);
    }
}

// ---------------- classifier head ----------------
__global__ void head_kernel(const float* __restrict__ cls, const float* __restrict__ w,
                            const float* __restrict__ hb, float* __restrict__ out) {
    int idx = blockIdx.x * 256 + threadIdx.x;
    if (idx >= BSZ * NCLS) return;
    int i = idx / NCLS, j = idx % NCLS;
    float acc = hb[j];
    const float* cr = cls + (size_t)i * 768;
    for (int k = 0; k < 768; ++k) acc += cr[k] * w[k * NCLS + j];
    out[idx] = acc;
}

extern "C" void kernel_launch(void* const* d_in, const int* in_sizes, int n_in,
                              void* d_out, int out_size, void* d_ws, size_t ws_size,
                              hipStream_t stream) {
    const float* x       = (const float*)d_in[0];
    const float* cls_tok = (const float*)d_in[1];
    const float* pos_emb = (const float*)d_in[2];
    const float* patch_w = (const float*)d_in[3];
    const float* patch_b = (const float*)d_in[4];
    const float* ln1_g   = (const float*)d_in[5];
    const float* ln1_b   = (const float*)d_in[6];
    const float* proj    = (const float*)d_in[7];
    const float* ln2_g   = (const float*)d_in[8];
    const float* ln2_b   = (const float*)d_in[9];
    const float* w1      = (const float*)d_in[10];
    const float* b1      = (const float*)d_in[11];
    const float* w2      = (const float*)d_in[12];
    const float* b2      = (const float*)d_in[13];
    const float* lnf_g   = (const float*)d_in[14];
    const float* lnf_b   = (const float*)d_in[15];
    const float* head_w  = (const float*)d_in[16];
    const float* head_b  = (const float*)d_in[17];
    float* out = (float*)d_out;

    char* wsb = (char*)d_ws;
    // region A (aliased): y1b [3200x3072 bf16] in loop; pre-loop: tok fp32 + patches bf16
    ushortT* y1b        = (ushortT*)wsb;                       // 19,660,800 B
    float*   tok        = (float*)wsb;                         // 9,633,792 B
    ushortT* patches_bf = (ushortT*)(wsb + 9633792);           // 4,915,200 B
    size_t off = 19660800;
    float*    h      = (float*)(wsb + off);    off += 9682944;   // [3152,768]
    float*    xln    = (float*)(wsb + off);    off += 9830400;   // [3200,768] fp32
    ushortT*  xln_bf = (ushortT*)(wsb + off);  off += 4915200;   // [3200,768] bf16
    float*    lg     = (float*)(wsb + off);    off += 3227648;   // [3152,256]
    float*    qf     = (float*)(wsb + off);    off += 3227648;
    float*    kv     = (float*)(wsb + off);    off += 12582912;  // [16,256,768]
    ushortT*  pwb    = (ushortT*)(wsb + off);  off += 1179648;   // [768,768] bf16
    ushortT*  projb  = (ushortT*)(wsb + off);  off += 4718592;   // [12,256,768] bf16
    float*    diag   = (float*)(wsb + off);    off += 12800;
    unsigned* gml    = (unsigned*)(wsb + off); off += 256;       // per-layer global max (encoded)
    float*    ksum   = (float*)(wsb + off);    off += 16384;
    float*    clsln  = (float*)(wsb + off);    off += 49152;
    const size_t WSTRIDE = (size_t)3072 * 768; // elements per layer weight
    ushortT*  w1t    = (ushortT*)(wsb + off);
    bool big = ws_size >= off + 2u * NLAY * WSTRIDE * sizeof(ushortT);
    size_t w1bytes = (big ? NLAY : 1) * WSTRIDE * sizeof(ushortT);
    ushortT*  w2t    = (ushortT*)(wsb + off + w1bytes);

    init_gmax<<<1, 64, 0, stream>>>(gml);

    // --- batched weight conversion (all layers upfront when ws allows) ---
    if (big) {
        transpose_cvt<<<dim3(96, 24, NLAY), 256, 0, stream>>>(w1, w1t, 768, FDIM);
        transpose_cvt<<<dim3(24, 96, NLAY), 256, 0, stream>>>(w2, w2t, FDIM, 768);
    }
    cvt_bf16<<<(NLAY * MDIM * EDIM + 255) / 256, 256, 0, stream>>>(proj, projb, NLAY * MDIM * EDIM);

    // --- patch embedding (bf16 MFMA, 64-tile: 588 blocks) ---
    gather_patches<<<9408, 256, 0, stream>>>(x, patches_bf);
    cvt_bf16<<<2304, 256, 0, stream>>>(patch_w, pwb, 768 * 768);
    mgemm64<0><<<dim3(12, 49), 256, 0, stream>>>(patches_bf, pwb, patch_b, nullptr, tok,
                                                 TPAT, 768, 768);
    assemble_kernel<<<9456, 256, 0, stream>>>(tok, cls_tok, pos_emb, h);

    // --- transformer layers ---
    for (int l = 0; l < NLAY; ++l) {
        ushortT* w1l = big ? w1t + (size_t)l * WSTRIDE : w1t;
        ushortT* w2l = big ? w2t + (size_t)l * WSTRIDE : w2t;
        if (!big) {
            transpose_cvt<<<dim3(96, 24), 256, 0, stream>>>(w1 + (size_t)l * WSTRIDE, w1l, 768, FDIM);
            transpose_cvt<<<dim3(24, 96), 256, 0, stream>>>(w2 + (size_t)l * WSTRIDE, w2l, FDIM, 768);
        }

        ln_kernel<<<TTOT, 256, 0, stream>>>(h, 768, ln1_g + l * 768, ln1_b + l * 768,
                                            xln, xln_bf, diag);
        mgemm64<3><<<dim3(4, 50), 256, 0, stream>>>(xln_bf, projb + (size_t)l * MDIM * EDIM,
                                                    nullptr, diag, lg, TTOT, 256, 768);
        rowqf_kernel<<<TTOT, 256, 0, stream>>>(lg, qf, gml + l);
        kv_kernel<<<BSZ * 32, 256, 0, stream>>>(lg, gml + l, xln, kv, ksum);
        att_ln2<<<BSZ * 25, 256, 0, stream>>>(qf, ksum, kv, h,
                                              ln2_g + l * 768, ln2_b + l * 768, xln_bf);
        mgemm128_gelu<<<dim3(24, 25), 256, 0, stream>>>(xln_bf, w1l, b1 + l * FDIM,
                                                        y1b, TTOT, FDIM, 768);
        mgemm64<2><<<dim3(12, 50), 256, 0, stream>>>(y1b, w2l, b2 + l * 768, nullptr,
                                                     h, TTOT, 768, FDIM);
    }

    // --- final LN on cls tokens + head ---
    ln_kernel<<<BSZ, 256, 0, stream>>>(h, NTOK * 768, lnf_g, lnf_b, clsln, xln_bf, nullptr);
    head_kernel<<<(BSZ * NCLS + 255) / 256, 256, 0, stream>>>(clsln, head_w, head_b, out);
}